// Round 5
// baseline (70.545 us; speedup 1.0000x reference)
//
#include <hip/hip_runtime.h>
#include <hip/hip_bf16.h>
#include <float.h>

#define B_ 64
#define C_ 512
#define Q_ 64
#define D_ 256

typedef _Float16 f16x8 __attribute__((ext_vector_type(8)));
typedef float f32x4 __attribute__((ext_vector_type(4)));

union U4H8 { uint4 u; f16x8 h; };
union UH2 { _Float16 h[2]; uint32_t u; };

__device__ __forceinline__ uint32_t packh2(float a, float b) {
  UH2 v; v.h[0] = (_Float16)a; v.h[1] = (_Float16)b; return v.u;
}
__device__ __forceinline__ float2 h2f2(uint32_t u) {
  UH2 v; v.u = u;
  float2 r; r.x = (float)v.h[0]; r.y = (float)v.h[1]; return r;
}

__device__ __forceinline__ float wred_sum(float v) {
#pragma unroll
  for (int off = 32; off > 0; off >>= 1) v += __shfl_xor(v, off, 64);
  return v;
}
__device__ __forceinline__ float wred_max(float v) {
#pragma unroll
  for (int off = 32; off > 0; off >>= 1) v = fmaxf(v, __shfl_xor(v, off, 64));
  return v;
}

// K_main (MFMA): block = 4 waves, wave = 16 c-rows. simT = mfma(q, ctx*wm),
// softmax over q in C/D layout, P -> LDS bounce, c2qT = mfma(qT, P) so each
// lane holds 4 consecutive d -> float4 epilogue stores.
// qbuf (32KB) time-shared: qraw (simT) then qT (c2q). qwq fused (from qraw).
// LDS = 32K + 8K + .5K = 41.5 KB -> 3 blocks/CU if VGPR <= ~168 (no clamp).
__global__ __launch_bounds__(256) void k_main(
    const float* __restrict__ ctx, const float* __restrict__ qst,
    const int* __restrict__ qmask, const float* __restrict__ w,
    float* __restrict__ g, float* __restrict__ simmax_g) {
  // phase 1 (qraw): [q][k] f16, rows of 256 = 32 chunks(16B); phys chunk low3 ^= (q&7)
  // phase 2 (qT):   [d][q] f16, rows of 64  =  8 chunks(16B); phys chunk      ^= (d&7)
  __shared__ __align__(16) ushort qbuf[Q_ * D_];
  // P per-wave: [c(16)][q(64)] f16, 8 chunks/row; phys chunk ^= (c&7)
  __shared__ __align__(16) ushort pbuf[4][16 * Q_];
  __shared__ float qwq_l[Q_];
  __shared__ int   qml_l[Q_];

  const int bid = blockIdx.x;
  const int b = bid & 63;           // XCD-swizzle: same-b blocks share an XCD
  const int c0 = (bid >> 6) * 64;
  const int t = threadIdx.x;
  const int wv = t >> 6, ln = t & 63;
  const int lc = ln & 15;           // A/B row-or-col lane field, C/D col
  const int lg = ln >> 4;           // k-group
  const int c0w = c0 + wv * 16;

  // ---- B-frags: this wave's 16 ctx rows * w_m (f16), fused g0-copy + fp32 cwc dot ----
  f16x8 bfrag[8];
  float cwc_p = 0.f;
  const float* crow = ctx + ((size_t)b * C_ + c0w + lc) * D_;
  float* grow0 = g + ((size_t)b * C_ + c0w + lc) * (4 * D_);
#pragma unroll
  for (int kk = 0; kk < 8; ++kk) {
    int kb = kk * 32 + lg * 8;
    float4 cv0 = *(const float4*)(crow + kb);
    float4 cv1 = *(const float4*)(crow + kb + 4);
    float4 wc0 = *(const float4*)(w + kb);
    float4 wc1 = *(const float4*)(w + kb + 4);
    float4 wm0 = *(const float4*)(w + 2 * D_ + kb);
    float4 wm1 = *(const float4*)(w + 2 * D_ + kb + 4);
    cwc_p += cv0.x * wc0.x + cv0.y * wc0.y + cv0.z * wc0.z + cv0.w * wc0.w
           + cv1.x * wc1.x + cv1.y * wc1.y + cv1.z * wc1.z + cv1.w * wc1.w;
    bfrag[kk][0] = (_Float16)(cv0.x * wm0.x);
    bfrag[kk][1] = (_Float16)(cv0.y * wm0.y);
    bfrag[kk][2] = (_Float16)(cv0.z * wm0.z);
    bfrag[kk][3] = (_Float16)(cv0.w * wm0.w);
    bfrag[kk][4] = (_Float16)(cv1.x * wm1.x);
    bfrag[kk][5] = (_Float16)(cv1.y * wm1.y);
    bfrag[kk][6] = (_Float16)(cv1.z * wm1.z);
    bfrag[kk][7] = (_Float16)(cv1.w * wm1.w);
    *(float4*)(grow0 + kb) = cv0;          // g[0:D] = ctx exact copy
    *(float4*)(grow0 + kb + 4) = cv1;
  }
  float cwc = cwc_p;
  cwc += __shfl_xor(cwc, 16, 64);
  cwc += __shfl_xor(cwc, 32, 64);          // full row dot for c = c0w+lc

  // ---- stage qraw (coalesced) ----
  const float* qb = qst + (size_t)b * Q_ * D_;
#pragma unroll 4
  for (int it = 0; it < 32; ++it) {
    int idx = it * 256 + t;
    int q = idx >> 7, jp = idx & 127;      // jp = f32-pair index
    float2 v = *(const float2*)(qb + q * D_ + 2 * jp);
    int ch = jp >> 2;
    int phys = (ch & ~7) | ((ch & 7) ^ (q & 7));
    *(uint32_t*)((char*)qbuf + q * 512 + phys * 16 + (jp & 3) * 4) = packh2(v.x, v.y);
  }
  if (t < Q_) qml_l[t] = qmask[b * Q_ + t];
  __syncthreads();

  // ---- fused qwq: thread t handles q = t>>2, 64-d slice s = t&3 ----
  {
    const int q = t >> 2, s4 = t & 3;
    float qp = 0.f;
#pragma unroll
    for (int jj = 0; jj < 8; ++jj) {
      int ch = s4 * 8 + jj;
      int phys = (ch & ~7) | ((ch & 7) ^ (q & 7));
      U4H8 a; a.u = *(const uint4*)((const char*)qbuf + q * 512 + phys * 16);
      int d0 = ch * 8;
      float4 w0 = *(const float4*)(w + D_ + d0);
      float4 w1 = *(const float4*)(w + D_ + d0 + 4);
      float2 f0 = h2f2(a.u.x), f1 = h2f2(a.u.y), f2 = h2f2(a.u.z), f3 = h2f2(a.u.w);
      qp += f0.x * w0.x + f0.y * w0.y + f1.x * w0.z + f1.y * w0.w
          + f2.x * w1.x + f2.y * w1.y + f3.x * w1.z + f3.y * w1.w;
    }
    qp += __shfl_xor(qp, 1, 64);
    qp += __shfl_xor(qp, 2, 64);
    if ((t & 3) == 0) qwq_l[q] = qp;
  }
  __syncthreads();

  // ---- simT[q, c] via MFMA: A = question rows (qraw), B = (ctx*wm) cols ----
  f32x4 sacc[4];
#pragma unroll
  for (int tq = 0; tq < 4; ++tq) sacc[tq] = f32x4{0.f, 0.f, 0.f, 0.f};
#pragma unroll
  for (int tq = 0; tq < 4; ++tq) {
    int q = 16 * tq + lc;
#pragma unroll
    for (int kk = 0; kk < 8; ++kk) {
      int ch = lg + 4 * kk;
      int phys = (ch & ~7) | ((ch & 7) ^ (q & 7));
      U4H8 a; a.u = *(const uint4*)((const char*)qbuf + q * 512 + phys * 16);
      sacc[tq] = __builtin_amdgcn_mfma_f32_16x16x32_f16(a.h, bfrag[kk], sacc[tq], 0, 0, 0);
    }
  }

  // ---- softmax over q (16 in-lane vals + xor16/xor32), P -> pbuf ----
  float vals[4][4];
  float rmax = -FLT_MAX;
#pragma unroll
  for (int tq = 0; tq < 4; ++tq) {
    float4 qw4 = *(const float4*)(qwq_l + 16 * tq + 4 * lg);
#pragma unroll
    for (int r = 0; r < 4; ++r) {
      float qv = (r == 0) ? qw4.x : (r == 1) ? qw4.y : (r == 2) ? qw4.z : qw4.w;
      vals[tq][r] = sacc[tq][r] + cwc + qv;
      rmax = fmaxf(rmax, vals[tq][r]);
    }
  }
  rmax = fmaxf(rmax, __shfl_xor(rmax, 16, 64));
  rmax = fmaxf(rmax, __shfl_xor(rmax, 32, 64));
  if (ln < 16) simmax_g[b * C_ + c0w + lc] = rmax;   // unmasked max (ref semantics)

  float mmax = -FLT_MAX;
#pragma unroll
  for (int tq = 0; tq < 4; ++tq) {
    int4 qm4 = *(const int4*)(qml_l + 16 * tq + 4 * lg);
#pragma unroll
    for (int r = 0; r < 4; ++r) {
      int m = (r == 0) ? qm4.x : (r == 1) ? qm4.y : (r == 2) ? qm4.z : qm4.w;
      vals[tq][r] = m ? vals[tq][r] : -FLT_MAX;
      mmax = fmaxf(mmax, vals[tq][r]);
    }
  }
  mmax = fmaxf(mmax, __shfl_xor(mmax, 16, 64));
  mmax = fmaxf(mmax, __shfl_xor(mmax, 32, 64));
  float esum = 0.f;
#pragma unroll
  for (int tq = 0; tq < 4; ++tq)
#pragma unroll
    for (int r = 0; r < 4; ++r) {
      vals[tq][r] = __expf(vals[tq][r] - mmax);      // masked -> exp(-huge) = 0
      esum += vals[tq][r];
    }
  esum += __shfl_xor(esum, 16, 64);
  esum += __shfl_xor(esum, 32, 64);
  float inv = 1.f / esum;
#pragma unroll
  for (int tq = 0; tq < 4; ++tq) {
    uint32_t p01 = packh2(vals[tq][0] * inv, vals[tq][1] * inv);
    uint32_t p23 = packh2(vals[tq][2] * inv, vals[tq][3] * inv);
    int qb4 = 16 * tq + 4 * lg;
    int phys = ((qb4 >> 3) ^ (lc & 7));
    char* dst = (char*)pbuf[wv] + lc * 128 + phys * 16 + (qb4 & 7) * 2;
    *(uint2*)dst = uint2{p01, p23};
  }
  __syncthreads();   // all simT reads of qbuf done

  // ---- restage qbuf as qT [d][q] (transposed; L2-hot re-read) ----
#pragma unroll 4
  for (int it = 0; it < 32; ++it) {
    int q = t & 63;
    int jp = (t >> 6) + 4 * it;
    float2 v = *(const float2*)(qb + q * D_ + 2 * jp);
    int d0 = 2 * jp, d1 = d0 + 1;
    UH2 h0; h0.h[0] = (_Float16)v.x;
    UH2 h1; h1.h[0] = (_Float16)v.y;
    *(ushort*)((char*)qbuf + d0 * 128 + (((q >> 3) ^ (d0 & 7)) << 4) + (q & 7) * 2) = (ushort)(h0.u & 0xffff);
    *(ushort*)((char*)qbuf + d1 * 128 + (((q >> 3) ^ (d1 & 7)) << 4) + (q & 7) * 2) = (ushort)(h1.u & 0xffff);
  }
  __syncthreads();   // qT ready

  // ---- c2qT[d, c] via MFMA: A = qT rows (d), B = P cols (c) ----
  // C/D: col = lc = c, rows = 4*lg + r = 4 consecutive d -> float4 stores.
  f16x8 pfragB[2];
#pragma unroll
  for (int ks = 0; ks < 2; ++ks) {
    int phys = (lg + 4 * ks) ^ (lc & 7);
    U4H8 a; a.u = *(const uint4*)((const char*)pbuf[wv] + lc * 128 + phys * 16);
    pfragB[ks] = a.h;
  }
  const float* crow2 = ctx + ((size_t)b * C_ + c0w + lc) * D_;
  float* grow = g + ((size_t)b * C_ + c0w + lc) * (4 * D_);
#pragma unroll 4
  for (int dt = 0; dt < 16; ++dt) {
    f32x4 acc = f32x4{0.f, 0.f, 0.f, 0.f};
#pragma unroll
    for (int ks = 0; ks < 2; ++ks) {
      int d = dt * 16 + lc;
      int phys = (lg + 4 * ks) ^ (d & 7);
      U4H8 aq; aq.u = *(const uint4*)((const char*)qbuf + d * 128 + phys * 16);
      acc = __builtin_amdgcn_mfma_f32_16x16x32_f16(aq.h, pfragB[ks], acc, 0, 0, 0);
    }
    int dcol = dt * 16 + 4 * lg;
    float4 cvv = *(const float4*)(crow2 + dcol);
    float4 c2qv{acc[0], acc[1], acc[2], acc[3]};
    *(float4*)(grow + D_ + dcol) = c2qv;                       // g[D:2D] = c2q
    float4 p2{cvv.x * c2qv.x, cvv.y * c2qv.y, cvv.z * c2qv.z, cvv.w * c2qv.w};
    *(float4*)(grow + 2 * D_ + dcol) = p2;                     // g[2D:3D] = ctx*c2q
  }
}

// K2: fused per-batch masked softmax over sim_max + partial q2c (no bl round-trip)
__global__ __launch_bounds__(256) void k_q2c_bs(const float* __restrict__ ctx,
                                                const float* __restrict__ simmax,
                                                const int* __restrict__ cmask,
                                                float* __restrict__ part) {
  int b = blockIdx.x, ch = blockIdx.y, t = threadIdx.x;
  int wv = t >> 6, ln = t & 63;
  __shared__ float bls[C_];
  __shared__ float sred[4];
  __shared__ float ssum[4];
  float v0 = simmax[b * C_ + t], v1 = simmax[b * C_ + 256 + t];
  if (!cmask[b * C_ + t]) v0 = -FLT_MAX;
  if (!cmask[b * C_ + 256 + t]) v1 = -FLT_MAX;
  float mx = wred_max(fmaxf(v0, v1));
  if (ln == 0) sred[wv] = mx;
  __syncthreads();
  float bm = fmaxf(fmaxf(sred[0], sred[1]), fmaxf(sred[2], sred[3]));
  float e0 = __expf(v0 - bm), e1 = __expf(v1 - bm);
  float ps = wred_sum(e0 + e1);
  if (ln == 0) ssum[wv] = ps;
  __syncthreads();
  float bs = ssum[0] + ssum[1] + ssum[2] + ssum[3];
  float invbs = 1.f / bs;
  bls[t] = e0 * invbs;
  bls[256 + t] = e1 * invbs;
  __syncthreads();
  float acc = 0.f;
  int cbeg = ch * 64;
#pragma unroll 4
  for (int c = cbeg; c < cbeg + 64; ++c)
    acc += bls[c] * ctx[((size_t)b * C_ + c) * D_ + t];
  part[((size_t)b * 8 + ch) * D_ + t] = acc;
}

// K3: reduce partials -> q2c (LDS) -> g[3D:4D] = ctx * q2c for 64 c-rows
__global__ __launch_bounds__(256) void k_g3q(const float* __restrict__ ctx,
                                             const float* __restrict__ part,
                                             float* __restrict__ g) {
  int b = blockIdx.x, ch = blockIdx.y, t = threadIdx.x;
  __shared__ float q2c_l[D_];
  float s = 0.f;
#pragma unroll
  for (int k = 0; k < 8; ++k) s += part[((size_t)b * 8 + k) * D_ + t];
  q2c_l[t] = s;
  __syncthreads();
  int d4 = t & 63;    // float4 index within row
  int ro = t >> 6;    // row offset 0..3
  float4 qv = *(const float4*)(q2c_l + 4 * d4);
#pragma unroll 4
  for (int it = 0; it < 16; ++it) {
    int c = ch * 64 + it * 4 + ro;
    float4 cv = *(const float4*)(ctx + ((size_t)b * C_ + c) * D_ + 4 * d4);
    float4 o{cv.x * qv.x, cv.y * qv.y, cv.z * qv.z, cv.w * qv.w};
    *(float4*)(g + ((size_t)b * C_ + c) * (4 * D_) + 3 * D_ + 4 * d4) = o;
  }
}

extern "C" void kernel_launch(void* const* d_in, const int* in_sizes, int n_in,
                              void* d_out, int out_size, void* d_ws, size_t ws_size,
                              hipStream_t stream) {
  const float* ctx   = (const float*)d_in[0];
  const float* qst   = (const float*)d_in[1];
  const int*   cmask = (const int*)d_in[2];
  const int*   qmask = (const int*)d_in[3];
  const float* w     = (const float*)d_in[4];
  float* g  = (float*)d_out;
  float* ws = (float*)d_ws;

  float* simmax = ws;             // B*C  = 32768
  float* part   = ws + 32768;     // B*8*D = 131072

  k_main<<<dim3(512), 256, 0, stream>>>(ctx, qst, qmask, w, g, simmax);
  k_q2c_bs<<<dim3(B_, 8), 256, 0, stream>>>(ctx, simmax, cmask, part);
  k_g3q<<<dim3(B_, 8), 256, 0, stream>>>(ctx, part, g);
}

// Round 6
// 65.783 us; speedup vs baseline: 1.0724x; 1.0724x over previous
//
#include <hip/hip_runtime.h>
#include <hip/hip_bf16.h>
#include <float.h>

#define B_ 64
#define C_ 512
#define Q_ 64
#define D_ 256

typedef _Float16 f16x8 __attribute__((ext_vector_type(8)));
typedef float f32x4 __attribute__((ext_vector_type(4)));

union U4H8 { uint4 u; f16x8 h; };
union UH2 { _Float16 h[2]; uint32_t u; };

__device__ __forceinline__ uint32_t packh2(float a, float b) {
  UH2 v; v.h[0] = (_Float16)a; v.h[1] = (_Float16)b; return v.u;
}

__device__ __forceinline__ float wred_sum(float v) {
#pragma unroll
  for (int off = 32; off > 0; off >>= 1) v += __shfl_xor(v, off, 64);
  return v;
}
__device__ __forceinline__ float wred_max(float v) {
#pragma unroll
  for (int off = 32; off > 0; off >>= 1) v = fmaxf(v, __shfl_xor(v, off, 64));
  return v;
}

// K1: out[row] = dot(src[row, 0:256], wgt[0:256])
__global__ __launch_bounds__(256) void k_rowdot(const float* __restrict__ src,
                                                const float* __restrict__ wgt,
                                                float* __restrict__ out, int nrows) {
  int wv = threadIdx.x >> 6, ln = threadIdx.x & 63;
  int row = blockIdx.x * 4 + wv;
  if (row >= nrows) return;
  float4 s4 = *(const float4*)(src + (size_t)row * D_ + 4 * ln);
  float4 w4 = *(const float4*)(wgt + 4 * ln);
  float p = s4.x * w4.x + s4.y * w4.y + s4.z * w4.z + s4.w * w4.w;
  p = wred_sum(p);
  if (ln == 0) out[row] = p;
}

// K2 (MFMA): block = 4 waves, wave = 16 c-rows. simT = mfma(q, ctx*wm),
// softmax over q in C/D layout, P -> LDS bounce, c2qT = mfma(qT, P) so each
// lane holds 4 consecutive d -> float4 epilogue stores.
// r3 staging (separate qraw/qT, one barrier) + r4 swapped float4 epilogue.
// LDS = 32K(qraw) + 32K(qT) + 8K(P) + .5K = ~74 KB -> 2 blocks/CU.
__global__ __launch_bounds__(256, 2) void k_main(
    const float* __restrict__ ctx, const float* __restrict__ qst,
    const int* __restrict__ qmask, const float* __restrict__ w,
    const float* __restrict__ qwq_g, float* __restrict__ g,
    float* __restrict__ simmax_g) {
  // qraw: [q][k] f16, rows of 256 = 32 chunks(16B); phys chunk low3 ^= (q&7)
  __shared__ __align__(16) ushort qraw[Q_ * D_];
  // qT: [d][q] f16, rows of 64 = 8 chunks(16B); phys chunk ^= (d&7)
  __shared__ __align__(16) ushort qT[D_ * Q_];
  // P per-wave: [c(16)][q(64)] f16, 8 chunks/row; phys chunk ^= (c&7)
  __shared__ __align__(16) ushort pbuf[4][16 * Q_];
  __shared__ float qwq_l[Q_];
  __shared__ int   qml_l[Q_];

  const int bid = blockIdx.x;
  const int b = bid & 63;           // XCD-swizzle: same-b blocks share an XCD
  const int c0 = (bid >> 6) * 64;
  const int t = threadIdx.x;
  const int wv = t >> 6, ln = t & 63;
  const int lc = ln & 15;           // A/B row-or-col lane field, C/D col
  const int lg = ln >> 4;           // k-group
  const int c0w = c0 + wv * 16;

  // ---- B-frags: this wave's 16 ctx rows * w_m (f16), fused g0-copy + fp32 cwc dot ----
  f16x8 bfrag[8];
  float cwc_p = 0.f;
  const float* crow = ctx + ((size_t)b * C_ + c0w + lc) * D_;
  float* grow0 = g + ((size_t)b * C_ + c0w + lc) * (4 * D_);
#pragma unroll
  for (int kk = 0; kk < 8; ++kk) {
    int kb = kk * 32 + lg * 8;
    float4 cv0 = *(const float4*)(crow + kb);
    float4 cv1 = *(const float4*)(crow + kb + 4);
    float4 wc0 = *(const float4*)(w + kb);
    float4 wc1 = *(const float4*)(w + kb + 4);
    float4 wm0 = *(const float4*)(w + 2 * D_ + kb);
    float4 wm1 = *(const float4*)(w + 2 * D_ + kb + 4);
    cwc_p += cv0.x * wc0.x + cv0.y * wc0.y + cv0.z * wc0.z + cv0.w * wc0.w
           + cv1.x * wc1.x + cv1.y * wc1.y + cv1.z * wc1.z + cv1.w * wc1.w;
    bfrag[kk][0] = (_Float16)(cv0.x * wm0.x);
    bfrag[kk][1] = (_Float16)(cv0.y * wm0.y);
    bfrag[kk][2] = (_Float16)(cv0.z * wm0.z);
    bfrag[kk][3] = (_Float16)(cv0.w * wm0.w);
    bfrag[kk][4] = (_Float16)(cv1.x * wm1.x);
    bfrag[kk][5] = (_Float16)(cv1.y * wm1.y);
    bfrag[kk][6] = (_Float16)(cv1.z * wm1.z);
    bfrag[kk][7] = (_Float16)(cv1.w * wm1.w);
    *(float4*)(grow0 + kb) = cv0;          // g[0:D] = ctx exact copy
    *(float4*)(grow0 + kb + 4) = cv1;
  }
  float cwc = cwc_p;
  cwc += __shfl_xor(cwc, 16, 64);
  cwc += __shfl_xor(cwc, 32, 64);          // full row dot for c = c0w+lc

  // ---- stage qraw (coalesced) ----
  const float* qb = qst + (size_t)b * Q_ * D_;
#pragma unroll 4
  for (int it = 0; it < 32; ++it) {
    int idx = it * 256 + t;
    int q = idx >> 7, jp = idx & 127;      // jp = f32-pair index
    float2 v = *(const float2*)(qb + q * D_ + 2 * jp);
    int ch = jp >> 2;
    int phys = (ch & ~7) | ((ch & 7) ^ (q & 7));
    *(uint32_t*)((char*)qraw + q * 512 + phys * 16 + (jp & 3) * 4) = packh2(v.x, v.y);
  }
  // ---- stage qT (transposed; scattered L2-hot reads) ----
#pragma unroll 4
  for (int it = 0; it < 32; ++it) {
    int q = t & 63;
    int jp = (t >> 6) + 4 * it;
    float2 v = *(const float2*)(qb + q * D_ + 2 * jp);
    int d0 = 2 * jp, d1 = d0 + 1;
    UH2 h0; h0.h[0] = (_Float16)v.x;
    UH2 h1; h1.h[0] = (_Float16)v.y;
    *(ushort*)((char*)qT + d0 * 128 + (((q >> 3) ^ (d0 & 7)) << 4) + (q & 7) * 2) = (ushort)(h0.u & 0xffff);
    *(ushort*)((char*)qT + d1 * 128 + (((q >> 3) ^ (d1 & 7)) << 4) + (q & 7) * 2) = (ushort)(h1.u & 0xffff);
  }
  if (t < Q_) { qwq_l[t] = qwq_g[b * Q_ + t]; qml_l[t] = qmask[b * Q_ + t]; }
  __syncthreads();

  // ---- simT[q, c] via MFMA: A = question rows (qraw), B = (ctx*wm) cols ----
  f32x4 sacc[4];
#pragma unroll
  for (int tq = 0; tq < 4; ++tq) sacc[tq] = f32x4{0.f, 0.f, 0.f, 0.f};
#pragma unroll
  for (int tq = 0; tq < 4; ++tq) {
    int q = 16 * tq + lc;
#pragma unroll
    for (int kk = 0; kk < 8; ++kk) {
      int ch = lg + 4 * kk;
      int phys = (ch & ~7) | ((ch & 7) ^ (q & 7));
      U4H8 a; a.u = *(const uint4*)((const char*)qraw + q * 512 + phys * 16);
      sacc[tq] = __builtin_amdgcn_mfma_f32_16x16x32_f16(a.h, bfrag[kk], sacc[tq], 0, 0, 0);
    }
  }

  // ---- softmax over q (16 in-lane vals + xor16/xor32), P -> pbuf ----
  float vals[4][4];
  float rmax = -FLT_MAX;
#pragma unroll
  for (int tq = 0; tq < 4; ++tq) {
    float4 qw4 = *(const float4*)(qwq_l + 16 * tq + 4 * lg);
#pragma unroll
    for (int r = 0; r < 4; ++r) {
      float qv = (r == 0) ? qw4.x : (r == 1) ? qw4.y : (r == 2) ? qw4.z : qw4.w;
      vals[tq][r] = sacc[tq][r] + cwc + qv;
      rmax = fmaxf(rmax, vals[tq][r]);
    }
  }
  rmax = fmaxf(rmax, __shfl_xor(rmax, 16, 64));
  rmax = fmaxf(rmax, __shfl_xor(rmax, 32, 64));
  if (ln < 16) simmax_g[b * C_ + c0w + lc] = rmax;   // unmasked max (ref semantics)

  float mmax = -FLT_MAX;
#pragma unroll
  for (int tq = 0; tq < 4; ++tq) {
    int4 qm4 = *(const int4*)(qml_l + 16 * tq + 4 * lg);
#pragma unroll
    for (int r = 0; r < 4; ++r) {
      int m = (r == 0) ? qm4.x : (r == 1) ? qm4.y : (r == 2) ? qm4.z : qm4.w;
      vals[tq][r] = m ? vals[tq][r] : -FLT_MAX;
      mmax = fmaxf(mmax, vals[tq][r]);
    }
  }
  mmax = fmaxf(mmax, __shfl_xor(mmax, 16, 64));
  mmax = fmaxf(mmax, __shfl_xor(mmax, 32, 64));
  float esum = 0.f;
#pragma unroll
  for (int tq = 0; tq < 4; ++tq)
#pragma unroll
    for (int r = 0; r < 4; ++r) {
      vals[tq][r] = __expf(vals[tq][r] - mmax);      // masked -> exp(-huge) = 0
      esum += vals[tq][r];
    }
  esum += __shfl_xor(esum, 16, 64);
  esum += __shfl_xor(esum, 32, 64);
  float inv = 1.f / esum;
#pragma unroll
  for (int tq = 0; tq < 4; ++tq) {
    uint32_t p01 = packh2(vals[tq][0] * inv, vals[tq][1] * inv);
    uint32_t p23 = packh2(vals[tq][2] * inv, vals[tq][3] * inv);
    int qb4 = 16 * tq + 4 * lg;
    int phys = ((qb4 >> 3) ^ (lc & 7));
    char* dst = (char*)pbuf[wv] + lc * 128 + phys * 16 + (qb4 & 7) * 2;
    *(uint2*)dst = uint2{p01, p23};
  }
  // pbuf[wv] is wave-private: no block barrier needed (compiler inserts lgkmcnt)

  // ---- c2qT[d, c] via MFMA: A = qT rows (d), B = P cols (c) ----
  // C/D: col = lc = c, rows = 4*lg + r = 4 consecutive d -> float4 stores.
  f16x8 pfragB[2];
#pragma unroll
  for (int ks = 0; ks < 2; ++ks) {
    int phys = (lg + 4 * ks) ^ (lc & 7);
    U4H8 a; a.u = *(const uint4*)((const char*)pbuf[wv] + lc * 128 + phys * 16);
    pfragB[ks] = a.h;
  }
  const float* crow2 = ctx + ((size_t)b * C_ + c0w + lc) * D_;
  float* grow = g + ((size_t)b * C_ + c0w + lc) * (4 * D_);
#pragma unroll 4
  for (int dt = 0; dt < 16; ++dt) {
    f32x4 acc = f32x4{0.f, 0.f, 0.f, 0.f};
#pragma unroll
    for (int ks = 0; ks < 2; ++ks) {
      int d = dt * 16 + lc;
      int phys = (lg + 4 * ks) ^ (d & 7);
      U4H8 aq; aq.u = *(const uint4*)((const char*)qT + d * 128 + phys * 16);
      acc = __builtin_amdgcn_mfma_f32_16x16x32_f16(aq.h, pfragB[ks], acc, 0, 0, 0);
    }
    int dcol = dt * 16 + 4 * lg;
    float4 cvv = *(const float4*)(crow2 + dcol);
    float4 c2qv{acc[0], acc[1], acc[2], acc[3]};
    *(float4*)(grow + D_ + dcol) = c2qv;                       // g[D:2D] = c2q
    float4 p2{cvv.x * c2qv.x, cvv.y * c2qv.y, cvv.z * c2qv.z, cvv.w * c2qv.w};
    *(float4*)(grow + 2 * D_ + dcol) = p2;                     // g[2D:3D] = ctx*c2q
  }
}

// K3: fused per-batch masked softmax over sim_max + partial q2c (no bl round-trip)
__global__ __launch_bounds__(256) void k_q2c_bs(const float* __restrict__ ctx,
                                                const float* __restrict__ simmax,
                                                const int* __restrict__ cmask,
                                                float* __restrict__ part) {
  int b = blockIdx.x, ch = blockIdx.y, t = threadIdx.x;
  int wv = t >> 6, ln = t & 63;
  __shared__ float bls[C_];
  __shared__ float sred[4];
  __shared__ float ssum[4];
  float v0 = simmax[b * C_ + t], v1 = simmax[b * C_ + 256 + t];
  if (!cmask[b * C_ + t]) v0 = -FLT_MAX;
  if (!cmask[b * C_ + 256 + t]) v1 = -FLT_MAX;
  float mx = wred_max(fmaxf(v0, v1));
  if (ln == 0) sred[wv] = mx;
  __syncthreads();
  float bm = fmaxf(fmaxf(sred[0], sred[1]), fmaxf(sred[2], sred[3]));
  float e0 = __expf(v0 - bm), e1 = __expf(v1 - bm);
  float ps = wred_sum(e0 + e1);
  if (ln == 0) ssum[wv] = ps;
  __syncthreads();
  float bs = ssum[0] + ssum[1] + ssum[2] + ssum[3];
  float invbs = 1.f / bs;
  bls[t] = e0 * invbs;
  bls[256 + t] = e1 * invbs;
  __syncthreads();
  float acc = 0.f;
  int cbeg = ch * 64;
#pragma unroll 4
  for (int c = cbeg; c < cbeg + 64; ++c)
    acc += bls[c] * ctx[((size_t)b * C_ + c) * D_ + t];
  part[((size_t)b * 8 + ch) * D_ + t] = acc;
}

// K3c: reduce partials -> q2c[b, d]
__global__ __launch_bounds__(256) void k_q2c_sum(const float* __restrict__ part,
                                                 float* __restrict__ q2c) {
  int b = blockIdx.x, t = threadIdx.x;
  float s = 0.f;
#pragma unroll
  for (int ch = 0; ch < 8; ++ch) s += part[((size_t)b * 8 + ch) * D_ + t];
  q2c[b * D_ + t] = s;
}

// K4: g[3D:4D] = ctx * q2c (broadcast over c)
__global__ __launch_bounds__(256) void k_g3(const float* __restrict__ ctx,
                                            const float* __restrict__ q2c,
                                            float* __restrict__ g) {
  size_t i = (size_t)blockIdx.x * 256 + threadIdx.x;  // over B*C*64 float4s
  int d4 = (int)(i & 63);
  size_t row = i >> 6;
  int b = (int)(row >> 9);
  float4 cv = *(const float4*)(ctx + row * D_ + 4 * d4);
  float4 qv = *(const float4*)(q2c + (size_t)b * D_ + 4 * d4);
  float4 o{cv.x * qv.x, cv.y * qv.y, cv.z * qv.z, cv.w * qv.w};
  *(float4*)(g + row * (4 * D_) + 3 * D_ + 4 * d4) = o;
}

extern "C" void kernel_launch(void* const* d_in, const int* in_sizes, int n_in,
                              void* d_out, int out_size, void* d_ws, size_t ws_size,
                              hipStream_t stream) {
  const float* ctx   = (const float*)d_in[0];
  const float* qst   = (const float*)d_in[1];
  const int*   cmask = (const int*)d_in[2];
  const int*   qmask = (const int*)d_in[3];
  const float* w     = (const float*)d_in[4];
  float* g  = (float*)d_out;
  float* ws = (float*)d_ws;

  float* qwq    = ws;             // B*Q   = 4096
  float* simmax = ws + 4096;      // B*C   = 32768
  float* part   = ws + 36864;     // B*8*D = 131072
  float* q2c    = ws + 167936;    // B*D   = 16384

  k_rowdot<<<dim3(B_ * Q_ / 4), 256, 0, stream>>>(qst, w + D_, qwq, B_ * Q_);
  k_main<<<dim3(512), 256, 0, stream>>>(ctx, qst, qmask, w, qwq, g, simmax);
  k_q2c_bs<<<dim3(B_, 8), 256, 0, stream>>>(ctx, simmax, cmask, part);
  k_q2c_sum<<<dim3(B_), 256, 0, stream>>>(part, q2c);
  k_g3<<<dim3(B_ * C_ * 64 / 256), 256, 0, stream>>>(ctx, q2c, g);
}